// Round 6
// baseline (256.757 us; speedup 1.0000x reference)
//
#include <hip/hip_runtime.h>
#include <math.h>

#define BB 64
#define SS 1024
#define VV 1024
#define DD 512

#define MAP_WORDS  ((size_t)BB * SS * VV)            // 67,108,864
#define STEP_WORDS ((size_t)BB * SS * SS)            // 67,108,864
#define TOT_WORDS  (MAP_WORDS + STEP_WORDS)          // 134,217,728
#define TOT_F4     (TOT_WORDS / 4)                   // 33,554,432
#define MAP_F4     (MAP_WORDS / 4)                   // 16,777,216

#define COPY_BLOCKS   16384
#define F4_PER_BLOCK  2048      // 32 KB per block; 8192 blocks cover map exactly
#define NGATES        (BB * 2)  // 128
#define TOTAL_BLOCKS  (COPY_BLOCKS + NGATES)

typedef float f32x4 __attribute__((ext_vector_type(4)));

__device__ __forceinline__ float gelu_tanh(float x) {
    const float k = 0.7978845608028654f; // sqrt(2/pi)
    float x3 = x * x * x;
    return 0.5f * x * (1.0f + tanhf(k * (x + 0.044715f * x3)));
}

// One dispatch: blocks [0,16384) copy 32KB each with 8-deep ILP;
// blocks [16384,16512) compute the two gate MLPs into ws (overlapped).
__global__ void __launch_bounds__(256)
fused_copy_gate_kernel(
    const f32x4* __restrict__ map_memory,
    const f32x4* __restrict__ step_memory,
    f32x4* __restrict__ out,
    const float* __restrict__ evidence,
    const int* __restrict__ marker_id,
    const int* __restrict__ source_idx,
    const int* __restrict__ source_mask,
    const int* __restrict__ target_symbol_idx,
    const int* __restrict__ target_symbol_mask,
    const int* __restrict__ target_value_idx,
    const int* __restrict__ target_value_mask,
    const float* __restrict__ map_W1, const float* __restrict__ map_b1,
    const float* __restrict__ map_W2, const float* __restrict__ map_b2,
    const float* __restrict__ step_W1, const float* __restrict__ step_b1,
    const float* __restrict__ step_W2, const float* __restrict__ step_b2,
    int* __restrict__ ws_idx, float* __restrict__ ws_g)
{
    const int blk = blockIdx.x;
    if (blk < COPY_BLOCKS) {
        // ---- copy path: 8 independent 16B loads, then 8 stores ----
        const size_t base = (size_t)blk * F4_PER_BLOCK + threadIdx.x;
        const f32x4* __restrict__ src =
            (blk < COPY_BLOCKS / 2) ? (map_memory + base)
                                    : (step_memory + (base - MAP_F4));
        f32x4* __restrict__ dst = out + base;
        f32x4 v0 = src[0 * 256];
        f32x4 v1 = src[1 * 256];
        f32x4 v2 = src[2 * 256];
        f32x4 v3 = src[3 * 256];
        f32x4 v4 = src[4 * 256];
        f32x4 v5 = src[5 * 256];
        f32x4 v6 = src[6 * 256];
        f32x4 v7 = src[7 * 256];
        dst[0 * 256] = v0;
        dst[1 * 256] = v1;
        dst[2 * 256] = v2;
        dst[3 * 256] = v3;
        dst[4 * 256] = v4;
        dst[5 * 256] = v5;
        dst[6 * 256] = v6;
        dst[7 * 256] = v7;
        return;
    }

    // ---- gate path: one block per (batch, head) ----
    const int gb   = blk - COPY_BLOCKS;
    const int b    = gb >> 1;
    const int head = gb & 1;
    const float* W1  = head ? step_W1 : map_W1;
    const float* b1  = head ? step_b1 : map_b1;
    const float* W2  = head ? step_W2 : map_W2;
    const float* b2v = head ? step_b2 : map_b2;

    __shared__ float ev[DD];
    __shared__ float wsum[4];

    const int tid = threadIdx.x;
    for (int i = tid; i < DD; i += 256) ev[i] = evidence[b * DD + i];
    __syncthreads();

    float acc = 0.0f;
    #pragma unroll
    for (int jj = 0; jj < DD; jj += 256) {
        const int j = jj + tid;
        float h = b1[j];
        #pragma unroll 8
        for (int k = 0; k < DD; ++k) {
            h = fmaf(ev[k], W1[k * DD + j], h);
        }
        h = gelu_tanh(h);
        acc = fmaf(h, W2[j], acc);
    }

    #pragma unroll
    for (int off = 32; off > 0; off >>= 1) acc += __shfl_down(acc, off, 64);
    if ((tid & 63) == 0) wsum[tid >> 6] = acc;
    __syncthreads();

    if (tid == 0) {
        float g = wsum[0] + wsum[1] + wsum[2] + wsum[3] + b2v[0];
        g = 1.0f / (1.0f + expf(-g));
        const int m  = marker_id[b];
        const bool sm = source_mask[b] != 0;
        int idx = -1;
        if (head == 0) {
            if (((m == 1) || (m == 2)) && sm && (target_value_mask[b] != 0)) {
                idx = b * (SS * VV) + source_idx[b] * VV + target_value_idx[b];
            }
        } else {
            if ((m == 3) && sm && (target_symbol_mask[b] != 0)) {
                idx = (int)MAP_WORDS + b * (SS * SS) + source_idx[b] * SS
                    + target_symbol_idx[b];
            }
        }
        ws_idx[gb] = idx;
        ws_g[gb]   = g;
    }
}

// Tiny tail: apply the 128 masked RMW adds after the copy has landed.
__global__ void __launch_bounds__(NGATES)
scatter_tail_kernel(const int* __restrict__ ws_idx,
                    const float* __restrict__ ws_g,
                    float* __restrict__ out)
{
    const int i = threadIdx.x;
    const int idx = ws_idx[i];
    if (idx >= 0) out[idx] += ws_g[i];
}

extern "C" void kernel_launch(void* const* d_in, const int* in_sizes, int n_in,
                              void* d_out, int out_size, void* d_ws, size_t ws_size,
                              hipStream_t stream) {
    const float* map_memory  = (const float*)d_in[0];
    const float* step_memory = (const float*)d_in[1];
    const float* evidence    = (const float*)d_in[2];
    const int* marker_id     = (const int*)d_in[3];
    const int* source_idx    = (const int*)d_in[4];
    const int* source_mask        = (const int*)d_in[5];
    const int* target_symbol_idx  = (const int*)d_in[6];
    const int* target_symbol_mask = (const int*)d_in[7];
    const int* target_value_idx   = (const int*)d_in[8];
    const int* target_value_mask  = (const int*)d_in[9];
    const float* map_W1  = (const float*)d_in[10];
    const float* map_b1  = (const float*)d_in[11];
    const float* map_W2  = (const float*)d_in[12];
    const float* map_b2  = (const float*)d_in[13];
    const float* step_W1 = (const float*)d_in[14];
    const float* step_b1 = (const float*)d_in[15];
    const float* step_W2 = (const float*)d_in[16];
    const float* step_b2 = (const float*)d_in[17];

    float* out = (float*)d_out;
    char* ws = (char*)d_ws;
    int*   ws_idx = (int*)ws;
    float* ws_g   = (float*)(ws + NGATES * sizeof(int));

    fused_copy_gate_kernel<<<dim3(TOTAL_BLOCKS), dim3(256), 0, stream>>>(
        (const f32x4*)map_memory, (const f32x4*)step_memory, (f32x4*)out,
        evidence, marker_id, source_idx, source_mask,
        target_symbol_idx, target_symbol_mask,
        target_value_idx, target_value_mask,
        map_W1, map_b1, map_W2, map_b2,
        step_W1, step_b1, step_W2, step_b2,
        ws_idx, ws_g);

    scatter_tail_kernel<<<dim3(1), dim3(NGATES), 0, stream>>>(ws_idx, ws_g, out);
}

// Round 7
// 236.799 us; speedup vs baseline: 1.0843x; 1.0843x over previous
//
#include <hip/hip_runtime.h>
#include <math.h>

#define BB 64
#define SS 1024
#define VV 1024
#define DD 512

#define MAP_WORDS  ((size_t)BB * SS * VV)            // 67,108,864
#define STEP_WORDS ((size_t)BB * SS * SS)            // 67,108,864
#define TOT_WORDS  (MAP_WORDS + STEP_WORDS)          // 134,217,728
#define TOT_F4     (TOT_WORDS / 4)                   // 33,554,432
#define MAP_F4     (MAP_WORDS / 4)                   // 16,777,216
#define STEP_F4    (STEP_WORDS / 4)                  // 16,777,216

#define COPY_BLOCKS  4096
#define NGATES       (BB * 2)                        // 128
#define TOTAL_BLOCKS (COPY_BLOCKS + NGATES)

typedef float f32x4 __attribute__((ext_vector_type(4)));

__device__ __forceinline__ float gelu_tanh(float x) {
    const float k = 0.7978845608028654f; // sqrt(2/pi)
    float x3 = x * x * x;
    return 0.5f * x * (1.0f + tanhf(k * (x + 0.044715f * x3)));
}

// Single dispatch: blocks [0,128) = gate MLPs (start at t=0, hidden under
// the copy); blocks [128, 128+4096) = NT grid-stride copy (R5's measured-
// best loop, unchanged).
__global__ void __launch_bounds__(256)
fused_gate_copy_kernel(
    const f32x4* __restrict__ map_memory,
    const f32x4* __restrict__ step_memory,
    f32x4* __restrict__ out,
    const float* __restrict__ evidence,
    const int* __restrict__ marker_id,
    const int* __restrict__ source_idx,
    const int* __restrict__ source_mask,
    const int* __restrict__ target_symbol_idx,
    const int* __restrict__ target_symbol_mask,
    const int* __restrict__ target_value_idx,
    const int* __restrict__ target_value_mask,
    const float* __restrict__ map_W1, const float* __restrict__ map_b1,
    const float* __restrict__ map_W2, const float* __restrict__ map_b2,
    const float* __restrict__ step_W1, const float* __restrict__ step_b1,
    const float* __restrict__ step_W2, const float* __restrict__ step_b2,
    int* __restrict__ ws_idx, float* __restrict__ ws_g)
{
    if (blockIdx.x >= NGATES) {
        // ---------------- copy path (R5 loop, NT grid-stride) ------------
        const int cblk = blockIdx.x - NGATES;
        const size_t stride = (size_t)COPY_BLOCKS * 256;
        const size_t tid0 = (size_t)cblk * 256 + threadIdx.x;
        #pragma unroll 4
        for (size_t i = tid0; i < MAP_F4; i += stride) {
            f32x4 v = __builtin_nontemporal_load(&map_memory[i]);
            __builtin_nontemporal_store(v, &out[i]);
        }
        #pragma unroll 4
        for (size_t i = tid0; i < STEP_F4; i += stride) {
            f32x4 v = __builtin_nontemporal_load(&step_memory[i]);
            __builtin_nontemporal_store(v, &out[MAP_F4 + i]);
        }
        return;
    }

    // ---------------- gate path: one block per (batch, head) -------------
    const int gb   = blockIdx.x;
    const int b    = gb >> 1;
    const int head = gb & 1;
    const float* W1  = head ? step_W1 : map_W1;
    const float* b1  = head ? step_b1 : map_b1;
    const float* W2  = head ? step_W2 : map_W2;
    const float* b2v = head ? step_b2 : map_b2;

    __shared__ float ev[DD];
    __shared__ float wsum[4];

    const int tid = threadIdx.x;
    for (int i = tid; i < DD; i += 256) ev[i] = evidence[b * DD + i];
    __syncthreads();

    float acc = 0.0f;
    #pragma unroll
    for (int jj = 0; jj < DD; jj += 256) {
        const int j = jj + tid;
        float h = b1[j];
        #pragma unroll 8
        for (int k = 0; k < DD; ++k) {
            h = fmaf(ev[k], W1[k * DD + j], h);
        }
        h = gelu_tanh(h);
        acc = fmaf(h, W2[j], acc);
    }

    #pragma unroll
    for (int off = 32; off > 0; off >>= 1) acc += __shfl_down(acc, off, 64);
    if ((tid & 63) == 0) wsum[tid >> 6] = acc;
    __syncthreads();

    if (tid == 0) {
        float g = wsum[0] + wsum[1] + wsum[2] + wsum[3] + b2v[0];
        g = 1.0f / (1.0f + expf(-g));
        const int m  = marker_id[b];
        const bool sm = source_mask[b] != 0;
        int idx = -1;
        if (head == 0) {
            if (((m == 1) || (m == 2)) && sm && (target_value_mask[b] != 0)) {
                idx = b * (SS * VV) + source_idx[b] * VV + target_value_idx[b];
            }
        } else {
            if ((m == 3) && sm && (target_symbol_mask[b] != 0)) {
                idx = (int)MAP_WORDS + b * (SS * SS) + source_idx[b] * SS
                    + target_symbol_idx[b];
            }
        }
        ws_idx[gb] = idx;
        ws_g[gb]   = g;
    }
}

// Tail: apply the 128 masked RMW adds after the copy has landed.
__global__ void __launch_bounds__(NGATES)
scatter_tail_kernel(const int* __restrict__ ws_idx,
                    const float* __restrict__ ws_g,
                    float* __restrict__ out)
{
    const int i = threadIdx.x;
    const int idx = ws_idx[i];
    if (idx >= 0) out[idx] += ws_g[i];
}

extern "C" void kernel_launch(void* const* d_in, const int* in_sizes, int n_in,
                              void* d_out, int out_size, void* d_ws, size_t ws_size,
                              hipStream_t stream) {
    const float* map_memory  = (const float*)d_in[0];
    const float* step_memory = (const float*)d_in[1];
    const float* evidence    = (const float*)d_in[2];
    const int* marker_id     = (const int*)d_in[3];
    const int* source_idx    = (const int*)d_in[4];
    const int* source_mask        = (const int*)d_in[5];
    const int* target_symbol_idx  = (const int*)d_in[6];
    const int* target_symbol_mask = (const int*)d_in[7];
    const int* target_value_idx   = (const int*)d_in[8];
    const int* target_value_mask  = (const int*)d_in[9];
    const float* map_W1  = (const float*)d_in[10];
    const float* map_b1  = (const float*)d_in[11];
    const float* map_W2  = (const float*)d_in[12];
    const float* map_b2  = (const float*)d_in[13];
    const float* step_W1 = (const float*)d_in[14];
    const float* step_b1 = (const float*)d_in[15];
    const float* step_W2 = (const float*)d_in[16];
    const float* step_b2 = (const float*)d_in[17];

    float* out = (float*)d_out;
    char* ws = (char*)d_ws;
    int*   ws_idx = (int*)ws;
    float* ws_g   = (float*)(ws + NGATES * sizeof(int));

    fused_gate_copy_kernel<<<dim3(TOTAL_BLOCKS), dim3(256), 0, stream>>>(
        (const f32x4*)map_memory, (const f32x4*)step_memory, (f32x4*)out,
        evidence, marker_id, source_idx, source_mask,
        target_symbol_idx, target_symbol_mask,
        target_value_idx, target_value_mask,
        map_W1, map_b1, map_W2, map_b2,
        step_W1, step_b1, step_W2, step_b2,
        ws_idx, ws_g);

    scatter_tail_kernel<<<dim3(1), dim3(NGATES), 0, stream>>>(ws_idx, ws_g, out);
}